// Round 1
// baseline (17243.839 us; speedup 1.0000x reference)
//
#include <hip/hip_runtime.h>
#include <hip/hip_bf16.h>

#define HID 512
#define NB  256   // batch
#define TT  256   // timesteps
#define DIN 64

// ---------------- zero workspace ----------------
__global__ __launch_bounds__(256) void zero_ws(float4* p, int n4) {
    int i = blockIdx.x * 256 + threadIdx.x;
    if (i < n4) p[i] = float4{0.f, 0.f, 0.f, 0.f};
}

// ---------------- one LSTM step (one layer) ----------------
// gates[b, n] = sum_k inp[b,k] Wih[n,k] + sum_k h_prev[b,k] Whh[n,k] + bih[n] + bhh[n]
// block: 16 batch x 32 hidden (all 4 gates). grid = (512/32, 256/16) = (16,16)
__global__ __launch_bounds__(256) void lstm_step(
    const float* __restrict__ inp, int inp_stride, int in_dim,
    const float* __restrict__ Wih, const float* __restrict__ Whh,
    const float* __restrict__ bih, const float* __restrict__ bhh,
    const float* __restrict__ h_prev, float* __restrict__ h_next,
    float* __restrict__ c)
{
    __shared__ float sIn[16][64];
    __shared__ float sW[128][65];   // +1 pad: conflict-free b32 reads
    const int tid  = threadIdx.x;
    const int j    = tid & 31;      // hidden col within tile
    const int brow = tid >> 5;      // 0..7
    const int jb   = blockIdx.x * 32;
    const int bb   = blockIdx.y * 16;

    float acc[2][4] = {{0.f,0.f,0.f,0.f},{0.f,0.f,0.f,0.f}};

    for (int phase = 0; phase < 2; ++phase) {
        const float* P  = phase ? h_prev : inp;
        const int    ps = phase ? HID : inp_stride;
        const int    kd = phase ? HID : in_dim;
        const float* W  = phase ? Whh : Wih;
        for (int kc = 0; kc < kd; kc += 64) {
            // stage input tile [16][64]
            {
                const int row = tid >> 4, c4 = (tid & 15) << 2;
                *(float4*)&sIn[row][c4] =
                    *(const float4*)(P + (size_t)(bb + row) * ps + kc + c4);
            }
            // stage weight tile [128][64]: rows n = g*512 + jb + (0..31)
            #pragma unroll
            for (int it = 0; it < 8; ++it) {
                const int idx = (it << 8) + tid;
                const int r = idx >> 4, c4 = (idx & 15) << 2;
                const int n = ((r >> 5) << 9) + jb + (r & 31);
                *(float4*)&sW[r][c4] =
                    *(const float4*)(W + (size_t)n * kd + kc + c4);
            }
            __syncthreads();
            #pragma unroll
            for (int k = 0; k < 64; ++k) {
                const float i0 = sIn[brow][k];
                const float i1 = sIn[brow + 8][k];
                #pragma unroll
                for (int g = 0; g < 4; ++g) {
                    const float wv = sW[(g << 5) + j][k];
                    acc[0][g] = fmaf(i0, wv, acc[0][g]);
                    acc[1][g] = fmaf(i1, wv, acc[1][g]);
                }
            }
            __syncthreads();
        }
    }

    const int jj = jb + j;
    const float bi = bih[jj]         + bhh[jj];
    const float bf = bih[512  + jj]  + bhh[512  + jj];
    const float bg = bih[1024 + jj]  + bhh[1024 + jj];
    const float bo = bih[1536 + jj]  + bhh[1536 + jj];
    #pragma unroll
    for (int r = 0; r < 2; ++r) {
        const int b = bb + brow + (r << 3);
        const float vi = acc[r][0] + bi;
        const float vf = acc[r][1] + bf;
        const float vg = acc[r][2] + bg;
        const float vo = acc[r][3] + bo;
        const float iG = 1.f / (1.f + expf(-vi));
        const float fG = 1.f / (1.f + expf(-vf));
        const float gG = tanhf(vg);
        const float oG = 1.f / (1.f + expf(-vo));
        const size_t off = (size_t)b * HID + jj;
        const float cv = fmaf(fG, c[off], iG * gG);
        c[off] = cv;
        h_next[off] = oG * tanhf(cv);
    }
}

// ---------------- head: out[b] = h1[b,:] . w + b ----------------
__global__ __launch_bounds__(64) void head_kernel(
    const float* __restrict__ h, const float* __restrict__ w,
    const float* __restrict__ b, float* __restrict__ out)
{
    const int bi = blockIdx.x, lane = threadIdx.x;
    float s = 0.f;
    #pragma unroll
    for (int k = lane; k < HID; k += 64) s += h[(size_t)bi * HID + k] * w[k];
    #pragma unroll
    for (int off = 32; off > 0; off >>= 1) s += __shfl_down(s, off);
    if (lane == 0) out[bi] = s + b[0];
}

extern "C" void kernel_launch(void* const* d_in, const int* in_sizes, int n_in,
                              void* d_out, int out_size, void* d_ws, size_t ws_size,
                              hipStream_t stream) {
    const float* x      = (const float*)d_in[0];
    const float* W_ih0  = (const float*)d_in[1];
    const float* W_hh0  = (const float*)d_in[2];
    const float* b_ih0  = (const float*)d_in[3];
    const float* b_hh0  = (const float*)d_in[4];
    const float* W_ih1  = (const float*)d_in[5];
    const float* W_hh1  = (const float*)d_in[6];
    const float* b_ih1  = (const float*)d_in[7];
    const float* b_hh1  = (const float*)d_in[8];
    const float* head_w = (const float*)d_in[9];
    const float* head_b = (const float*)d_in[10];
    float* out = (float*)d_out;
    float* ws  = (float*)d_ws;

    // ws layout (floats): h0a h0b h1a h1b c0 c1, each 256*512 = 131072
    float* h0a = ws;
    float* h0b = ws + 131072;
    float* h1a = ws + 262144;
    float* h1b = ws + 393216;
    float* c0  = ws + 524288;
    float* c1  = ws + 655360;
    const int total_f = 786432;          // 3 MB of state
    zero_ws<<<(total_f / 4 + 255) / 256, 256, 0, stream>>>((float4*)ws, total_f / 4);

    dim3 grid(16, 16);
    float* h0c = h0a; float* h0n = h0b;
    float* h1c = h1a; float* h1n = h1b;
    for (int t = 0; t < TT; ++t) {
        // layer 0: input = x[:, t, :]  (row stride T*DIN)
        lstm_step<<<grid, 256, 0, stream>>>(x + (size_t)t * DIN, TT * DIN, DIN,
                                            W_ih0, W_hh0, b_ih0, b_hh0,
                                            h0c, h0n, c0);
        // layer 1: input = h0_next (= ys0[:, t, :])
        lstm_step<<<grid, 256, 0, stream>>>(h0n, HID, HID,
                                            W_ih1, W_hh1, b_ih1, b_hh1,
                                            h1c, h1n, c1);
        float* tmp;
        tmp = h0c; h0c = h0n; h0n = tmp;
        tmp = h1c; h1c = h1n; h1n = tmp;
    }
    // after final swap, h1c holds h_last of layer 1
    head_kernel<<<NB, 64, 0, stream>>>(h1c, head_w, head_b, out);
}

// Round 2
// 6007.238 us; speedup vs baseline: 2.8705x; 2.8705x over previous
//
#include <hip/hip_runtime.h>

#define HID 512
#define NB  256
#define TT  256
#define DIN 64

typedef __attribute__((ext_vector_type(8))) short short8;
typedef __attribute__((ext_vector_type(4))) float f32x4;

__device__ __forceinline__ unsigned short f2bf(float f) {
    unsigned int u = __float_as_uint(f);
    u += 0x7FFF + ((u >> 16) & 1);          // round-to-nearest-even
    return (unsigned short)(u >> 16);
}
__device__ __forceinline__ float bf2f(unsigned short h) {
    return __uint_as_float(((unsigned int)h) << 16);
}

// ---------- fp32 -> bf16 hi/lo split ----------
__global__ __launch_bounds__(256) void cvt_hilo(const float* __restrict__ src,
                                                unsigned short* __restrict__ hi,
                                                unsigned short* __restrict__ lo, int n) {
    int i = blockIdx.x * 256 + threadIdx.x;
    if (i < n) {
        float f = src[i];
        unsigned short h = f2bf(f);
        hi[i] = h;
        lo[i] = f2bf(f - bf2f(h));
    }
}

// ---------- bias sums ----------
__global__ __launch_bounds__(256) void bias2(const float* a0, const float* b0, float* o0,
                                             const float* a1, const float* b1, float* o1) {
    int i = blockIdx.x * 256 + threadIdx.x;
    if (i < 2048) { o0[i] = a0[i] + b0[i]; o1[i] = a1[i] + b1[i]; }
}

// ---------- one LSTM step, MFMA bf16 hi/lo split ----------
// gates[b,n] = A[b,:]*Wih[n,:]^T + Hp[b,:]*Whh[n,:]^T + bsum[n]; fused c/h update.
// Block tile: 32 b x (4 gates x 16 j). grid = (512/16 j, 256/32 b) = (32, 8).
// 4 waves: wave w -> btile = w>>1, gates {2*(w&1), 2*(w&1)+1}.
template<bool XF32>
__global__ __launch_bounds__(256) void lstm_step(
    const float* __restrict__ Xf,            // XF32: fp32 input base (pre-offset by t)
    const unsigned short* __restrict__ Xh,   // !XF32: bf16-hi input
    const unsigned short* __restrict__ Xl,
    int xstride, int K0,
    const unsigned short* __restrict__ Wih_h, const unsigned short* __restrict__ Wih_l,
    const unsigned short* __restrict__ Whh_h, const unsigned short* __restrict__ Whh_l,
    const unsigned short* __restrict__ Hp_h,  const unsigned short* __restrict__ Hp_l,
    const float* __restrict__ bsum,
    float* __restrict__ c,
    unsigned short* __restrict__ Hn_h, unsigned short* __restrict__ Hn_l)
{
    __shared__ __align__(16) unsigned short sAh[32][64], sAl[32][64];
    __shared__ __align__(16) unsigned short sBh[64][64], sBl[64][64];
    __shared__ float sG[32][65];

    const int tid   = threadIdx.x;
    const int lane  = tid & 63;
    const int w     = tid >> 6;
    const int btile = w >> 1;
    const int gpair = (w & 1) * 2;
    const int j0    = blockIdx.x * 16;
    const int b0    = blockIdx.y * 32;

    f32x4 acc0 = {0.f, 0.f, 0.f, 0.f};
    f32x4 acc1 = {0.f, 0.f, 0.f, 0.f};

    const int srow = tid >> 3;   // 0..31
    const int sk8  = tid & 7;    // 0..7

    for (int phase = 0; phase < 2; ++phase) {
        const int K = phase ? HID : K0;
        const unsigned short* Wh = phase ? Whh_h : Wih_h;
        const unsigned short* Wl = phase ? Whh_l : Wih_l;
        for (int kc = 0; kc < K; kc += 64) {
            __syncthreads();
            // ---- stage A tile [32][64] (hi/lo), XOR-swizzled 16B units
            {
                const int slot = (sk8 ^ (srow & 7)) * 8;
                if (XF32 && phase == 0) {
                    const float* src = Xf + (size_t)(b0 + srow) * xstride + kc + sk8 * 8;
                    float vv[8];
                    *(float4*)&vv[0] = *(const float4*)src;
                    *(float4*)&vv[4] = *(const float4*)(src + 4);
                    union { unsigned short u[8]; uint4 v; } ph, pl;
                    #pragma unroll
                    for (int i = 0; i < 8; ++i) {
                        unsigned short h = f2bf(vv[i]);
                        ph.u[i] = h;
                        pl.u[i] = f2bf(vv[i] - bf2f(h));
                    }
                    *(uint4*)&sAh[srow][slot] = ph.v;
                    *(uint4*)&sAl[srow][slot] = pl.v;
                } else {
                    const unsigned short* srch = phase ? Hp_h : Xh;
                    const unsigned short* srcl = phase ? Hp_l : Xl;
                    const int stride = phase ? HID : xstride;
                    const size_t o = (size_t)(b0 + srow) * stride + kc + sk8 * 8;
                    *(uint4*)&sAh[srow][slot] = *(const uint4*)(srch + o);
                    *(uint4*)&sAl[srow][slot] = *(const uint4*)(srcl + o);
                }
            }
            // ---- stage B tile [64][64]: local row lr -> weight row n = (lr>>4)*512 + j0 + (lr&15)
            #pragma unroll
            for (int half = 0; half < 2; ++half) {
                const int lr = srow + half * 32;
                const int n  = ((lr >> 4) << 9) + j0 + (lr & 15);
                const size_t o = (size_t)n * K + kc + sk8 * 8;
                const int slot = (sk8 ^ (lr & 7)) * 8;
                *(uint4*)&sBh[lr][slot] = *(const uint4*)(Wh + o);
                *(uint4*)&sBl[lr][slot] = *(const uint4*)(Wl + o);
            }
            __syncthreads();
            // ---- MFMA: 2 k-steps of 32, split-3 per gate
            const int arow = btile * 16 + (lane & 15);
            const int br0  = gpair * 16 + (lane & 15);
            const int br1  = br0 + 16;
            #pragma unroll
            for (int kk = 0; kk < 2; ++kk) {
                const int u = kk * 4 + (lane >> 4);
                short8 ah  = *(const short8*)&sAh[arow][((u ^ (arow & 7))) * 8];
                short8 al  = *(const short8*)&sAl[arow][((u ^ (arow & 7))) * 8];
                short8 bh0 = *(const short8*)&sBh[br0][((u ^ (br0 & 7))) * 8];
                short8 bl0 = *(const short8*)&sBl[br0][((u ^ (br0 & 7))) * 8];
                short8 bh1 = *(const short8*)&sBh[br1][((u ^ (br1 & 7))) * 8];
                short8 bl1 = *(const short8*)&sBl[br1][((u ^ (br1 & 7))) * 8];
                acc0 = __builtin_amdgcn_mfma_f32_16x16x32_bf16(ah, bh0, acc0, 0, 0, 0);
                acc0 = __builtin_amdgcn_mfma_f32_16x16x32_bf16(ah, bl0, acc0, 0, 0, 0);
                acc0 = __builtin_amdgcn_mfma_f32_16x16x32_bf16(al, bh0, acc0, 0, 0, 0);
                acc1 = __builtin_amdgcn_mfma_f32_16x16x32_bf16(ah, bh1, acc1, 0, 0, 0);
                acc1 = __builtin_amdgcn_mfma_f32_16x16x32_bf16(ah, bl1, acc1, 0, 0, 0);
                acc1 = __builtin_amdgcn_mfma_f32_16x16x32_bf16(al, bh1, acc1, 0, 0, 0);
            }
        }
    }
    __syncthreads();
    // ---- regroup gates through LDS (C layout: col=lane&15, row=(lane>>4)*4+r)
    #pragma unroll
    for (int r = 0; r < 4; ++r) {
        const int brow = btile * 16 + (lane >> 4) * 4 + r;
        sG[brow][(gpair    ) * 16 + (lane & 15)] = acc0[r];
        sG[brow][(gpair + 1) * 16 + (lane & 15)] = acc1[r];
    }
    __syncthreads();
    // ---- fused bias + activations + c/h update (2 outputs/thread)
    #pragma unroll
    for (int p = tid; p < 512; p += 256) {
        const int bl = p >> 4, jj = p & 15;
        const int b = b0 + bl, j = j0 + jj;
        const float gi = sG[bl][jj]          + bsum[j];
        const float gf = sG[bl][16 + jj]     + bsum[512 + j];
        const float gg = sG[bl][32 + jj]     + bsum[1024 + j];
        const float go = sG[bl][48 + jj]     + bsum[1536 + j];
        const float iG = 1.f / (1.f + expf(-gi));
        const float fG = 1.f / (1.f + expf(-gf));
        const float gGt = tanhf(gg);
        const float oG = 1.f / (1.f + expf(-go));
        const size_t off = (size_t)b * HID + j;
        const float cv = fmaf(fG, c[off], iG * gGt);
        c[off] = cv;
        const float h = oG * tanhf(cv);
        const unsigned short hh = f2bf(h);
        Hn_h[off] = hh;
        Hn_l[off] = f2bf(h - bf2f(hh));
    }
}

// ---------- head ----------
__global__ __launch_bounds__(64) void head_kernel(
    const unsigned short* __restrict__ h_hi, const unsigned short* __restrict__ h_lo,
    const float* __restrict__ w, const float* __restrict__ bb, float* __restrict__ out)
{
    const int b = blockIdx.x, lane = threadIdx.x;
    float s = 0.f;
    #pragma unroll
    for (int k = lane; k < HID; k += 64)
        s += (bf2f(h_hi[(size_t)b * HID + k]) + bf2f(h_lo[(size_t)b * HID + k])) * w[k];
    #pragma unroll
    for (int off = 32; off > 0; off >>= 1) s += __shfl_down(s, off);
    if (lane == 0) out[b] = s + bb[0];
}

extern "C" void kernel_launch(void* const* d_in, const int* in_sizes, int n_in,
                              void* d_out, int out_size, void* d_ws, size_t ws_size,
                              hipStream_t stream) {
    const float* x      = (const float*)d_in[0];
    const float* W_ih0  = (const float*)d_in[1];
    const float* W_hh0  = (const float*)d_in[2];
    const float* b_ih0  = (const float*)d_in[3];
    const float* b_hh0  = (const float*)d_in[4];
    const float* W_ih1  = (const float*)d_in[5];
    const float* W_hh1  = (const float*)d_in[6];
    const float* b_ih1  = (const float*)d_in[7];
    const float* b_hh1  = (const float*)d_in[8];
    const float* head_w = (const float*)d_in[9];
    const float* head_b = (const float*)d_in[10];
    float* out = (float*)d_out;

    unsigned short* ws16 = (unsigned short*)d_ws;
    size_t o = 0;
    auto a16 = [&](size_t n) { unsigned short* p = ws16 + o; o += n; return p; };
    unsigned short* Wih0_h = a16(2048 * 64);
    unsigned short* Wih0_l = a16(2048 * 64);
    unsigned short* Whh0_h = a16(2048 * 512);
    unsigned short* Whh0_l = a16(2048 * 512);
    unsigned short* Wih1_h = a16(2048 * 512);
    unsigned short* Wih1_l = a16(2048 * 512);
    unsigned short* Whh1_h = a16(2048 * 512);
    unsigned short* Whh1_l = a16(2048 * 512);
    // zero-region A: t=0 h inputs (hi/lo for both layers), contiguous
    unsigned short* h0A_h = a16(NB * HID);
    unsigned short* h0A_l = a16(NB * HID);
    unsigned short* h1A_h = a16(NB * HID);
    unsigned short* h1A_l = a16(NB * HID);
    unsigned short* h0B_h = a16(NB * HID);
    unsigned short* h0B_l = a16(NB * HID);
    unsigned short* h1B_h = a16(NB * HID);
    unsigned short* h1B_l = a16(NB * HID);
    float* wsf = (float*)(ws16 + o);
    float* c0    = wsf;                 // zero-region B: c0,c1 contiguous
    float* c1    = wsf + NB * HID;
    float* bsum0 = wsf + 2 * NB * HID;
    float* bsum1 = bsum0 + 2048;

    // ---- precompute (every call; deterministic) ----
    cvt_hilo<<<(2048 * 64) / 256, 256, 0, stream>>>(W_ih0, Wih0_h, Wih0_l, 2048 * 64);
    cvt_hilo<<<(2048 * 512) / 256, 256, 0, stream>>>(W_hh0, Whh0_h, Whh0_l, 2048 * 512);
    cvt_hilo<<<(2048 * 512) / 256, 256, 0, stream>>>(W_ih1, Wih1_h, Wih1_l, 2048 * 512);
    cvt_hilo<<<(2048 * 512) / 256, 256, 0, stream>>>(W_hh1, Whh1_h, Whh1_l, 2048 * 512);
    bias2<<<8, 256, 0, stream>>>(b_ih0, b_hh0, bsum0, b_ih1, b_hh1, bsum1);
    hipMemsetAsync(h0A_h, 0, 4 * NB * HID * sizeof(unsigned short), stream);
    hipMemsetAsync(c0, 0, 2 * NB * HID * sizeof(float), stream);

    // ---- recurrence ----
    dim3 grid(HID / 16, NB / 32);
    unsigned short *h0c_h = h0A_h, *h0c_l = h0A_l, *h0n_h = h0B_h, *h0n_l = h0B_l;
    unsigned short *h1c_h = h1A_h, *h1c_l = h1A_l, *h1n_h = h1B_h, *h1n_l = h1B_l;
    for (int t = 0; t < TT; ++t) {
        lstm_step<true><<<grid, 256, 0, stream>>>(
            x + (size_t)t * DIN, nullptr, nullptr, TT * DIN, DIN,
            Wih0_h, Wih0_l, Whh0_h, Whh0_l, h0c_h, h0c_l, bsum0, c0, h0n_h, h0n_l);
        lstm_step<false><<<grid, 256, 0, stream>>>(
            nullptr, h0n_h, h0n_l, HID, HID,
            Wih1_h, Wih1_l, Whh1_h, Whh1_l, h1c_h, h1c_l, bsum1, c1, h1n_h, h1n_l);
        unsigned short* tp;
        tp = h0c_h; h0c_h = h0n_h; h0n_h = tp;
        tp = h0c_l; h0c_l = h0n_l; h0n_l = tp;
        tp = h1c_h; h1c_h = h1n_h; h1n_h = tp;
        tp = h1c_l; h1c_l = h1n_l; h1n_l = tp;
    }
    head_kernel<<<NB, 64, 0, stream>>>(h1c_h, h1c_l, head_w, head_b, out);
}